// Round 5
// baseline (469.396 us; speedup 1.0000x reference)
//
#include <hip/hip_runtime.h>

#define VOCAB 50000
#define SEQ   200
#define NF4   (VOCAB / 4)   // 12500 float4 stores per row

// Native clang vector type: __builtin_nontemporal_store requires a scalar,
// pointer, or native vector -- HIP's float4 class does not qualify.
typedef float floatx4 __attribute__((ext_vector_type(4)));

// One block per batch row. Write-once structure: the 409.6 MB output is
// 99.6% zeros, so the store stream is a pure register zero-fill (same shape
// as the runtime's fillBufferAligned, which measures 5.75 TB/s on this
// chip), and the <=200 nonzero buckets are patched afterwards with ONE
// scattered 4B store per distinct bucket. Duplicate tokens are resolved
// in-block with an O(SEQ^2) compare loop over an 800 B LDS index array
// (LDS broadcast reads are conflict-free; ~1K VALU cycles, hidden under
// the store stream's vmcnt backpressure). No global atomics, no 50 KB LDS
// histogram (800 B -> 8 blocks/CU), no ds_read/unpack on the store path.
__global__ __launch_bounds__(256) void MultihotEmbedding_16458314678493_kernel(
    const int* __restrict__ x, float* __restrict__ out) {
  __shared__ int lidx[SEQ];

  const int row = blockIdx.x;
  const int t = threadIdx.x;
  float* __restrict__ orow = out + (size_t)row * VOCAB;

  // Phase A: stage this row's 200 token indices into LDS.
  if (t < SEQ) lidx[t] = x[row * SEQ + t];
  __syncthreads();

  // Phase B: dense zero-fill of the row. Nontemporal full-line streaming
  // stores of a zero register -- nothing to fetch, nothing to unpack.
  floatx4* __restrict__ o4 = (floatx4*)orow;
  const floatx4 z = {0.f, 0.f, 0.f, 0.f};
  for (int i = t; i < NF4; i += 256) __builtin_nontemporal_store(z, &o4[i]);

  // Phase C (overlaps with the store drain): per-token count + first-
  // occurrence flag. All lanes read the same lidx[j] each iter -> LDS
  // broadcast, free.
  int myidx = -1, cnt = 0, first = 1;
  if (t < SEQ) myidx = lidx[t];
  for (int j = 0; j < SEQ; ++j) {
    const int ij = lidx[j];
    if (ij == myidx) {
      cnt++;
      if (j < t) first = 0;
    }
  }

  // Phase D: barrier drains vmcnt -> all zero-stores complete at L2.
  // Then one plain 4B store per distinct bucket (no RMW, no race: only the
  // first occurrence writes, and it carries the full duplicate count).
  __syncthreads();
  if (t < SEQ && first) orow[myidx] = (float)cnt;
}

extern "C" void kernel_launch(void* const* d_in, const int* in_sizes, int n_in,
                              void* d_out, int out_size, void* d_ws, size_t ws_size,
                              hipStream_t stream) {
  const int* x = (const int*)d_in[0];
  float* out = (float*)d_out;
  const int batch = in_sizes[0] / SEQ;  // 2048
  MultihotEmbedding_16458314678493_kernel<<<batch, 256, 0, stream>>>(x, out);
}

// Round 6
// 412.737 us; speedup vs baseline: 1.1373x; 1.1373x over previous
//
#include <hip/hip_runtime.h>

#define VOCAB 50000
#define SEQ   200
#define NF4   (VOCAB / 4)      // 12500 float4 stores per row
#define NHW   (VOCAB / 8)      // 6250 u32 words of 4-bit counts (25 KB)

// One block per batch row, ONE-PASS structure: every output line is written
// exactly once, carrying its final value -- no second touch, no global
// atomics, no post-stream barrier/patch tail (the tail was worth +20..40us
// in rounds 2/3/5). Counts live in a 4-bit LDS histogram:
//   25 KB + 800 B -> 6 blocks/CU (vs 3 for the old 50 KB u8 version).
// The histogram is built race-free: a O(SEQ^2) LDS-broadcast compare loop
// gives each token its duplicate count + first-occurrence flag; each
// distinct token ORs its count nibble (distinct buckets -> distinct
// nibbles, so atomicOr composes exactly). Counts >15 (prob ~1e-3 over the
// whole dataset) are made exact by a block-uniform overflow patch pass.
__global__ __launch_bounds__(256) void MultihotEmbedding_16458314678493_kernel(
    const int* __restrict__ x, float* __restrict__ out) {
  __shared__ unsigned hist[NHW];
  __shared__ int lidx[SEQ];
  __shared__ int ovf;

  const int row = blockIdx.x;
  const int t = threadIdx.x;
  float* __restrict__ orow = out + (size_t)row * VOCAB;

  // Phase A: zero the nibble histogram + stage this row's indices.
  for (int i = t; i < NHW; i += 256) hist[i] = 0u;
  if (t < SEQ) lidx[t] = x[row * SEQ + t];
  if (t == 0) ovf = 0;
  __syncthreads();

  // Phase B: dedupe-count (all lanes read the same lidx[j] -> LDS
  // broadcast, conflict-free), then one atomicOr per distinct token.
  int myidx = -1, cnt = 0, first = 1;
  if (t < SEQ) myidx = lidx[t];
  for (int j = 0; j < SEQ; ++j) {
    const int ij = lidx[j];
    if (ij == myidx) {
      cnt++;
      if (j < t) first = 0;
    }
  }
  if (t < SEQ && first) {
    atomicOr(&hist[myidx >> 3],
             (unsigned)(cnt < 15 ? cnt : 15) << ((myidx & 7) * 4));
    if (cnt > 15) atomicExch(&ovf, 1);
  }
  __syncthreads();

  // Phase C: single uninterrupted store stream with final values.
  // Lane i reads hist word i>>1: pairs broadcast, 32 distinct words across
  // the wave -> conflict-free. 4x bfe + 4x cvt per 16B store (trivial VALU
  // against the store budget).
  float4* __restrict__ o4 = (float4*)orow;
  for (int i = t; i < NF4; i += 256) {
    const unsigned nib = hist[i >> 1] >> ((i & 1) * 16);
    float4 v;
    v.x = (float)(nib & 0xFu);
    v.y = (float)((nib >> 4) & 0xFu);
    v.z = (float)((nib >> 8) & 0xFu);
    v.w = (float)((nib >> 12) & 0xFu);
    o4[i] = v;
  }

  // Phase D: exact-overflow patch (count > 15). Block-uniform branch, ~never
  // taken; the barrier (vmcnt drain) only executes on the overflow path.
  if (ovf) {
    __syncthreads();
    if (t < SEQ && first && cnt > 15) orow[myidx] = (float)cnt;
  }
}

extern "C" void kernel_launch(void* const* d_in, const int* in_sizes, int n_in,
                              void* d_out, int out_size, void* d_ws, size_t ws_size,
                              hipStream_t stream) {
  const int* x = (const int*)d_in[0];
  float* out = (float*)d_out;
  const int batch = in_sizes[0] / SEQ;  // 2048
  MultihotEmbedding_16458314678493_kernel<<<batch, 256, 0, stream>>>(x, out);
}

// Round 7
// 412.248 us; speedup vs baseline: 1.1386x; 1.0012x over previous
//
#include <hip/hip_runtime.h>

#define VOCAB 50000
#define SEQ   200
#define NF4   (VOCAB / 4)      // 12500 float4 stores per row
#define NHW   (VOCAB / 16)     // 3125 u32 words of 2-bit counts (12.5 KB)

// One block per batch row, ONE-PASS structure (R6 winner, tuned): every
// output line is written exactly once with its final value. Histogram is
// now 2-BIT counts: 12.5 KB + 800 B LDS -> 8 blocks/CU (the 32-wave cap),
// so ALL 2048 blocks are resident in a single dispatch round (R6's 25 KB
// nibble version capped at 6/CU -> 1536 + a 512-block partial-machine
// tail). Counts follow from the O(SEQ^2) LDS-broadcast dedupe loop (now
// int4-chunked: 50 ds_read_b128 broadcasts instead of 200 b32); each
// distinct token ORs its 2-bit field (distinct buckets -> distinct fields,
// OR composes exactly). Counts > 3 (expected ~2 rows in the whole dataset;
// dup-pair rate ~0.4/row) stay exact via the block-uniform patch pass.
__global__ __launch_bounds__(256) void MultihotEmbedding_16458314678493_kernel(
    const int* __restrict__ x, float* __restrict__ out) {
  __shared__ unsigned hist[NHW];
  __shared__ int lidx[SEQ];
  __shared__ int ovf;

  const int row = blockIdx.x;
  const int t = threadIdx.x;
  float* __restrict__ orow = out + (size_t)row * VOCAB;

  // Phase A: zero the 2-bit histogram (13 iters) + stage indices (int4).
  for (int i = t; i < NHW; i += 256) hist[i] = 0u;
  if (t < SEQ / 4) ((int4*)lidx)[t] = ((const int4*)(x + row * SEQ))[t];
  if (t == 0) ovf = 0;
  __syncthreads();

  // Phase B: dedupe-count. int4 broadcast reads (all lanes same address ->
  // free), 200 compares per thread. first = (my position is the row's
  // first occurrence); cnt = total duplicates of my token.
  int myidx = -1, cnt = 0, first = 1;
  if (t < SEQ) myidx = lidx[t];
  for (int jj = 0; jj < SEQ / 4; ++jj) {
    const int4 q = ((const int4*)lidx)[jj];
    const int j0 = jj * 4;
    if (q.x == myidx) { cnt++; if (j0 + 0 < t) first = 0; }
    if (q.y == myidx) { cnt++; if (j0 + 1 < t) first = 0; }
    if (q.z == myidx) { cnt++; if (j0 + 2 < t) first = 0; }
    if (q.w == myidx) { cnt++; if (j0 + 3 < t) first = 0; }
  }
  if (t < SEQ && first) {
    atomicOr(&hist[myidx >> 4],
             (unsigned)(cnt < 3 ? cnt : 3) << ((myidx & 15) * 2));
    if (cnt > 3) atomicOr((unsigned*)&ovf, 1u);
  }
  __syncthreads();

  // Phase C: single uninterrupted store stream with final values.
  // Lane i reads hist[i>>2]: 4-lane same-address broadcast groups over 16
  // distinct banks -> conflict-free. Unpack = 1 shift + 4 bfe + 4 cvt.
  float4* __restrict__ o4 = (float4*)orow;
  for (int i = t; i < NF4; i += 256) {
    const unsigned b = (hist[i >> 2] >> ((i & 3) * 8)) & 0xFFu;
    float4 v;
    v.x = (float)(b & 3u);
    v.y = (float)((b >> 2) & 3u);
    v.z = (float)((b >> 4) & 3u);
    v.w = (float)((b >> 6) & 3u);
    o4[i] = v;
  }

  // Phase D: exact-overflow patch (count > 3). Block-uniform, ~never taken.
  if (ovf) {
    __syncthreads();
    if (t < SEQ && first && cnt > 3) orow[myidx] = (float)cnt;
  }
}

extern "C" void kernel_launch(void* const* d_in, const int* in_sizes, int n_in,
                              void* d_out, int out_size, void* d_ws, size_t ws_size,
                              hipStream_t stream) {
  const int* x = (const int*)d_in[0];
  float* out = (float*)d_out;
  const int batch = in_sizes[0] / SEQ;  // 2048
  MultihotEmbedding_16458314678493_kernel<<<batch, 256, 0, stream>>>(x, out);
}